// Round 1
// baseline (426.254 us; speedup 1.0000x reference)
//
#include <hip/hip_runtime.h>
#include <hip/hip_bf16.h>

// Problem constants (hardcoded from reference)
#define T_ 6
#define Q_ 300
#define TQ 1800
#define D_ 256
#define NH_ 8
#define DH_ 32
#define L_ 4
#define P_ 7
#define DFF_ 1024
#define NV 130560   // 6 * (128*128 + 64*64 + 32*32 + 16*16)

typedef __attribute__((ext_vector_type(8))) short bf16x8;
typedef __attribute__((ext_vector_type(4))) float f32x4;

__device__ inline unsigned short f2bf(float f) {
    union { float f; unsigned u; } v; v.f = f;
    unsigned u = v.u;
    unsigned r = (u + 0x7FFFu + ((u >> 16) & 1u)) >> 16;
    return (unsigned short)r;
}
__device__ inline float bf2f(unsigned short s) {
    union { unsigned u; float f; } v; v.u = ((unsigned)s) << 16;
    return v.f;
}

// ---------------------------------------------------------------------------
// Generic GEMM: out[M,N] = (A (+A2)) @ W^T + bias, bf16 MFMA, fp32 accumulate.
// A: M x K fp32 row-major.  W: N x K fp32 row-major.  out fp32 or bf16.
// Block: 256 thr = 4 waves in 2x2; wave tile 32x32 via 2x2 of 16x16x32 mfma.
// ---------------------------------------------------------------------------
template<int RELU, int ADD2, int OUTBF16>
__global__ __launch_bounds__(256) void gemm_kernel(
    const float* __restrict__ A, const float* __restrict__ A2,
    const float* __restrict__ W, const float* __restrict__ bias,
    void* __restrict__ outp, int M, int N, int K)
{
    int wave = threadIdx.x >> 6;
    int lane = threadIdx.x & 63;
    int wm = wave >> 1, wn = wave & 1;
    int m0 = blockIdx.x * 64 + wm * 32;
    int n0 = blockIdx.y * 64 + wn * 32;
    int r = lane & 15;   // A row / B col within 16
    int g = lane >> 4;   // k group (x8)

    f32x4 acc[2][2] = {};

    for (int kk = 0; kk < K; kk += 32) {
        int kbase = kk + g * 8;
        bf16x8 af[2], wf[2];
#pragma unroll
        for (int mi = 0; mi < 2; mi++) {
            int row = m0 + mi * 16 + r; if (row >= M) row = M - 1;
            const float* ap = A + (size_t)row * K + kbase;
            if (ADD2) {
                const float* ap2 = A2 + (size_t)row * K + kbase;
#pragma unroll
                for (int j = 0; j < 8; j++) af[mi][j] = (short)f2bf(ap[j] + ap2[j]);
            } else {
#pragma unroll
                for (int j = 0; j < 8; j++) af[mi][j] = (short)f2bf(ap[j]);
            }
        }
#pragma unroll
        for (int ni = 0; ni < 2; ni++) {
            int col = n0 + ni * 16 + r; if (col >= N) col = N - 1;
            const float* wp = W + (size_t)col * K + kbase;
#pragma unroll
            for (int j = 0; j < 8; j++) wf[ni][j] = (short)f2bf(wp[j]);
        }
#pragma unroll
        for (int mi = 0; mi < 2; mi++)
#pragma unroll
            for (int ni = 0; ni < 2; ni++)
                acc[mi][ni] = __builtin_amdgcn_mfma_f32_16x16x32_bf16(af[mi], wf[ni], acc[mi][ni], 0, 0, 0);
    }

    float* outf = (float*)outp;
    unsigned short* outb = (unsigned short*)outp;
#pragma unroll
    for (int mi = 0; mi < 2; mi++)
#pragma unroll
        for (int ni = 0; ni < 2; ni++) {
            int col = n0 + ni * 16 + r;
            if (col < N) {
                float bv = bias ? bias[col] : 0.f;
#pragma unroll
                for (int rr = 0; rr < 4; rr++) {
                    int row = m0 + mi * 16 + g * 4 + rr;
                    if (row < M) {
                        float v = acc[mi][ni][rr] + bv;
                        if (RELU) v = fmaxf(v, 0.f);
                        size_t idx = (size_t)row * N + col;
                        if (OUTBF16) outb[idx] = f2bf(v); else outf[idx] = v;
                    }
                }
            }
        }
}

// ---------------------------------------------------------------------------
// Self-attention over T=6 frames, per (query, head). One block per q (300).
// threads: tid = h*32 + d  (h in [0,8), d in [0,32))
// ---------------------------------------------------------------------------
__global__ __launch_bounds__(256) void selfattn_kernel(
    const float* __restrict__ qh, const float* __restrict__ kh,
    const float* __restrict__ vh, float* __restrict__ sa)
{
    int q = blockIdx.x;
    int tid = threadIdx.x;
    __shared__ float qs[T_][D_], ks[T_][D_], vs[T_][D_];
#pragma unroll
    for (int i = 0; i < T_; i++) {
        size_t base = (size_t)(i * Q_ + q) * D_ + tid;
        qs[i][tid] = qh[base]; ks[i][tid] = kh[base]; vs[i][tid] = vh[base];
    }
    __syncthreads();

    const float scale = 0.17677669529663687f; // 1/sqrt(32)
    float lg[T_][T_];
#pragma unroll
    for (int i = 0; i < T_; i++)
#pragma unroll
        for (int j = 0; j < T_; j++) {
            float p = qs[i][tid] * ks[j][tid];
#pragma unroll
            for (int m = 16; m >= 1; m >>= 1) p += __shfl_xor(p, m, 32);
            lg[i][j] = p * scale;
        }
    float o[T_];
#pragma unroll
    for (int i = 0; i < T_; i++) {
        float mx = lg[i][0];
#pragma unroll
        for (int j = 1; j < T_; j++) mx = fmaxf(mx, lg[i][j]);
        float w[T_]; float sum = 0.f;
#pragma unroll
        for (int j = 0; j < T_; j++) { w[j] = __expf(lg[i][j] - mx); sum += w[j]; }
        float inv = 1.f / sum;
        float a = 0.f;
#pragma unroll
        for (int j = 0; j < T_; j++) a += w[j] * inv * vs[j][tid];
        o[i] = a;
    }
#pragma unroll
    for (int i = 0; i < T_; i++) sa[(size_t)(i * Q_ + q) * D_ + tid] = o[i];
}

// ---------------------------------------------------------------------------
// LayerNorm: out = LN(x1 + x2) * g + b ; optionally out2 = out + add2.
// One block (256 thr) per row of 256.
// ---------------------------------------------------------------------------
__global__ __launch_bounds__(256) void ln_kernel(
    const float* __restrict__ x1, const float* __restrict__ x2,
    const float* __restrict__ gam, const float* __restrict__ bet,
    float* __restrict__ out, const float* __restrict__ add2, float* __restrict__ out2)
{
    int row = blockIdx.x;
    int tid = threadIdx.x;
    size_t idx = (size_t)row * D_ + tid;
    float v = x1[idx] + x2[idx];
    __shared__ float red[4];
    float s = v;
#pragma unroll
    for (int m = 32; m >= 1; m >>= 1) s += __shfl_xor(s, m, 64);
    if ((tid & 63) == 0) red[tid >> 6] = s;
    __syncthreads();
    float mu = (red[0] + red[1] + red[2] + red[3]) * (1.f / 256.f);
    __syncthreads();
    float dv = v - mu;
    float s2 = dv * dv;
#pragma unroll
    for (int m = 32; m >= 1; m >>= 1) s2 += __shfl_xor(s2, m, 64);
    if ((tid & 63) == 0) red[tid >> 6] = s2;
    __syncthreads();
    float var = (red[0] + red[1] + red[2] + red[3]) * (1.f / 256.f);
    float y = dv * rsqrtf(var + 1e-5f) * gam[tid] + bet[tid];
    out[idx] = y;
    if (out2) out2[idx] = y + add2[idx];
}

// ---------------------------------------------------------------------------
// Deformable sampling + attention-weighted accumulation.
// One block per flat query q (1800). tid = h*32 + d.
// value: NV x 256 bf16.  attl: raw attention logits (TQ x 224).
// off: TQ x 448.  out: TQ x 256 fp32.
// ---------------------------------------------------------------------------
__global__ __launch_bounds__(256) void sample_kernel(
    const unsigned short* __restrict__ value, const float* __restrict__ attl,
    const float* __restrict__ off, const float* __restrict__ refp,
    const float* __restrict__ vr, float* __restrict__ out)
{
    int q = blockIdx.x;
    int tid = threadIdx.x;
    int d = tid & 31, h = tid >> 5;
    int t = q / Q_, qq = q - t * Q_;

    __shared__ float aw[NH_][28], ofx[NH_][28], ofy[NH_][28];

    float lgv = (d < 28) ? attl[(size_t)q * 224 + h * 28 + d] : -1e30f;
    float mx = lgv;
#pragma unroll
    for (int m = 16; m >= 1; m >>= 1) mx = fmaxf(mx, __shfl_xor(mx, m, 32));
    float e = (d < 28) ? __expf(lgv - mx) : 0.f;
    float s = e;
#pragma unroll
    for (int m = 16; m >= 1; m >>= 1) s += __shfl_xor(s, m, 32);
    if (d < 28) {
        aw[h][d] = e / s;
        ofx[h][d] = off[(size_t)q * 448 + h * 56 + d * 2 + 0];
        ofy[h][d] = off[(size_t)q * 448 + h * 56 + d * 2 + 1];
    }
    __syncthreads();

    const int WLs[4] = {128, 64, 32, 16};
    const int LST[4] = {0, 98304, 122880, 129024};

    float acc = 0.f;
#pragma unroll
    for (int l = 0; l < L_; l++) {
        const int Wl = WLs[l], Hl = WLs[l];
        const int lst = LST[l];
        float vrx = vr[l * 2 + 0], vry = vr[l * 2 + 1];
#pragma unroll
        for (int p = 0; p < P_; p++) {
            int f = (p < 2) ? t : (((p - 2) < t) ? (p - 2) : (p - 1));
            float rx = refp[(size_t)(f * Q_ + qq) * 2 + 0];
            float ry = refp[(size_t)(f * Q_ + qq) * 2 + 1];
            int ip = l * 7 + p;
            float x = rx * vrx * (float)Wl + ofx[h][ip] - 0.5f;
            float y = ry * vry * (float)Hl + ofy[h][ip] - 0.5f;
            float x0f = floorf(x), y0f = floorf(y);
            float fx = x - x0f, fy = y - y0f;
            int x0 = (int)x0f, y0 = (int)y0f;
            int fbase = lst + f * Hl * Wl;
            float a = aw[h][ip];
#pragma unroll
            for (int dy = 0; dy < 2; dy++) {
                int yi = y0 + dy;
                float wy = dy ? fy : 1.f - fy;
                int yc = min(max(yi, 0), Hl - 1);
                bool oky = (yi >= 0) && (yi < Hl);
#pragma unroll
                for (int dx = 0; dx < 2; dx++) {
                    int xi = x0 + dx;
                    float wx = dx ? fx : 1.f - fx;
                    int xc = min(max(xi, 0), Wl - 1);
                    bool ok = oky && (xi >= 0) && (xi < Wl);
                    float v = bf2f(value[((size_t)(fbase + yc * Wl + xc)) * D_ + h * DH_ + d]);
                    acc += a * (ok ? (wy * wx) : 0.f) * v;
                }
            }
        }
    }
    out[(size_t)q * D_ + tid] = acc;
}

// ---------------------------------------------------------------------------
extern "C" void kernel_launch(void* const* d_in, const int* in_sizes, int n_in,
                              void* d_out, int out_size, void* d_ws, size_t ws_size,
                              hipStream_t stream) {
    const float* src  = (const float*)d_in[0];
    const float* tgtm = (const float*)d_in[1];
    const float* qpos = (const float*)d_in[2];
    const float* refp = (const float*)d_in[3];
    const float* vr   = (const float*)d_in[4];   // use frame-0 slice: first 8 floats
    const float* Wq = (const float*)d_in[7];  const float* bq = (const float*)d_in[8];
    const float* Wk = (const float*)d_in[9];  const float* bk = (const float*)d_in[10];
    const float* Wv = (const float*)d_in[11]; const float* bv = (const float*)d_in[12];
    const float* Wo = (const float*)d_in[13]; const float* bo = (const float*)d_in[14];
    const float* n2g = (const float*)d_in[15]; const float* n2b = (const float*)d_in[16];
    const float* Wval = (const float*)d_in[17]; const float* bval = (const float*)d_in[18];
    const float* Woff = (const float*)d_in[19]; const float* boff = (const float*)d_in[20];
    const float* Watt = (const float*)d_in[21]; const float* batt = (const float*)d_in[22];
    const float* Wout = (const float*)d_in[23]; const float* bout = (const float*)d_in[24];
    const float* n1g = (const float*)d_in[25]; const float* n1b = (const float*)d_in[26];
    const float* W1 = (const float*)d_in[27]; const float* b1 = (const float*)d_in[28];
    const float* W2 = (const float*)d_in[29]; const float* b2 = (const float*)d_in[30];
    const float* n3g = (const float*)d_in[31]; const float* n3b = (const float*)d_in[32];

    char* ws = (char*)d_ws;
    size_t o = 0;
    auto alloc = [&](size_t bytes) -> void* {
        void* p = ws + o; o += (bytes + 255) & ~(size_t)255; return p;
    };
    unsigned short* value = (unsigned short*)alloc((size_t)NV * D_ * 2);
    float* qh     = (float*)alloc((size_t)TQ * D_ * 4);
    float* kh     = (float*)alloc((size_t)TQ * D_ * 4);
    float* vh     = (float*)alloc((size_t)TQ * D_ * 4);
    float* sa_raw = (float*)alloc((size_t)TQ * D_ * 4);
    float* saproj = (float*)alloc((size_t)TQ * D_ * 4);
    float* tgt1   = (float*)alloc((size_t)TQ * D_ * 4);
    float* query  = (float*)alloc((size_t)TQ * D_ * 4);
    float* offb   = (float*)alloc((size_t)TQ * 448 * 4);
    float* attl   = (float*)alloc((size_t)TQ * 224 * 4);
    float* samp   = (float*)alloc((size_t)TQ * D_ * 4);
    float* cross  = (float*)alloc((size_t)TQ * D_ * 4);
    float* tgt2   = (float*)alloc((size_t)TQ * D_ * 4);
    float* hbuf   = (float*)alloc((size_t)TQ * DFF_ * 4);
    float* ffo    = (float*)alloc((size_t)TQ * D_ * 4);

    dim3 B(256);
    const int MT = (TQ + 63) / 64;  // 29

    // Big value projection (independent of everything else): NV x 256, bf16 out
    gemm_kernel<0,0,1><<<dim3(NV / 64, 4), B, 0, stream>>>(src, nullptr, Wval, bval, value, NV, D_, D_);

    // Self-attention branch
    gemm_kernel<0,1,0><<<dim3(MT, 4), B, 0, stream>>>(tgtm, qpos, Wq, bq, qh, TQ, D_, D_);
    gemm_kernel<0,1,0><<<dim3(MT, 4), B, 0, stream>>>(tgtm, qpos, Wk, bk, kh, TQ, D_, D_);
    gemm_kernel<0,0,0><<<dim3(MT, 4), B, 0, stream>>>(tgtm, nullptr, Wv, bv, vh, TQ, D_, D_);
    selfattn_kernel<<<dim3(Q_), B, 0, stream>>>(qh, kh, vh, sa_raw);
    gemm_kernel<0,0,0><<<dim3(MT, 4), B, 0, stream>>>(sa_raw, nullptr, Wo, bo, saproj, TQ, D_, D_);
    ln_kernel<<<dim3(TQ), B, 0, stream>>>(tgtm, saproj, n2g, n2b, tgt1, qpos, query);

    // Deformable cross-attention
    gemm_kernel<0,0,0><<<dim3(MT, 7), B, 0, stream>>>(query, nullptr, Woff, boff, offb, TQ, 448, D_);
    gemm_kernel<0,0,0><<<dim3(MT, 4), B, 0, stream>>>(query, nullptr, Watt, batt, attl, TQ, 224, D_);
    sample_kernel<<<dim3(TQ), B, 0, stream>>>(value, attl, offb, refp, vr, samp);
    gemm_kernel<0,0,0><<<dim3(MT, 4), B, 0, stream>>>(samp, nullptr, Wout, bout, cross, TQ, D_, D_);
    ln_kernel<<<dim3(TQ), B, 0, stream>>>(tgt1, cross, n1g, n1b, tgt2, nullptr, nullptr);

    // FFN
    gemm_kernel<1,0,0><<<dim3(MT, 16), B, 0, stream>>>(tgt2, nullptr, W1, b1, hbuf, TQ, DFF_, D_);
    gemm_kernel<0,0,0><<<dim3(MT, 4), B, 0, stream>>>(hbuf, nullptr, W2, b2, ffo, TQ, D_, DFF_);
    ln_kernel<<<dim3(TQ), B, 0, stream>>>(tgt2, ffo, n3g, n3b, (float*)d_out, nullptr, nullptr);
}

// Round 2
// 242.141 us; speedup vs baseline: 1.7604x; 1.7604x over previous
//
#include <hip/hip_runtime.h>
#include <hip/hip_bf16.h>

// Problem constants (hardcoded from reference)
#define T_ 6
#define Q_ 300
#define TQ 1800
#define D_ 256
#define NH_ 8
#define DH_ 32
#define L_ 4
#define P_ 7
#define DFF_ 1024
#define NV 130560   // 6 * (128*128 + 64*64 + 32*32 + 16*16)

typedef __attribute__((ext_vector_type(8))) short bf16x8;
typedef __attribute__((ext_vector_type(4))) float f32x4;
typedef __attribute__((ext_vector_type(8))) unsigned short u16x8;

__device__ inline unsigned short f2bf(float f) {
    union { float f; unsigned u; } v; v.f = f;
    unsigned u = v.u;
    unsigned r = (u + 0x7FFFu + ((u >> 16) & 1u)) >> 16;
    return (unsigned short)r;
}
__device__ inline float bf2f(unsigned short s) {
    union { unsigned u; float f; } v; v.u = ((unsigned)s) << 16;
    return v.f;
}
__device__ inline unsigned short f2b_rn(float f) {
    __hip_bfloat16 h = __float2bfloat16(f);
    union { __hip_bfloat16 h; unsigned short u; } c; c.h = h; return c.u;
}

// ---------------------------------------------------------------------------
// Value GEMM: out[NV,256] (bf16) = A[NV,256] (fp32) @ W[256,256]^T (fp32) + bias
// BM=128, BN=256 (full N -> A fetched once). 512 threads = 8 waves (2x4),
// wave tile 64x64 = 4x4 frags of 16x16x32. Reg-staged fp32->bf16 conversion,
// double-buffered LDS, early-issued loads, one barrier per K-step.
// ---------------------------------------------------------------------------
__global__ __launch_bounds__(512) void vgemm_kernel(
    const float* __restrict__ A, const float* __restrict__ W,
    const float* __restrict__ bias, unsigned short* __restrict__ out)
{
    __shared__ unsigned short As[2][128 * 32];
    __shared__ unsigned short Bs[2][256 * 32];

    int tid = threadIdx.x;
    int wave = tid >> 6, lane = tid & 63;
    int wm = wave >> 2, wn = wave & 3;
    int r = lane & 15, g = lane >> 4;
    int m0 = blockIdx.x * 128;

    // staging: A tile 128x32 fp32, 8 floats/thread (4 threads per row)
    int arow = tid >> 2, aq = tid & 3;
    const float* aptr = A + (size_t)(m0 + arow) * 256 + aq * 8;
    // staging: B tile 256x32 fp32, 16 floats/thread (2 threads per col)
    int bcol = tid >> 1, bh = tid & 1;
    const float* bptr = W + (size_t)bcol * 256 + bh * 16;

    f32x4 a0, a1, b0, b1, b2, b3;
#define ISSUE(kk) do { \
        a0 = *(const f32x4*)(aptr + (kk)); \
        a1 = *(const f32x4*)(aptr + (kk) + 4); \
        b0 = *(const f32x4*)(bptr + (kk)); \
        b1 = *(const f32x4*)(bptr + (kk) + 4); \
        b2 = *(const f32x4*)(bptr + (kk) + 8); \
        b3 = *(const f32x4*)(bptr + (kk) + 12); \
    } while (0)

    f32x4 acc[4][4] = {};

    ISSUE(0);
#pragma unroll
    for (int ks = 0; ks < 8; ks++) {
        int buf = ks & 1;
        // convert + ds_write (compiler inserts vmcnt waits on a0..b3)
        {
            u16x8 av;
#pragma unroll
            for (int j = 0; j < 4; j++) { av[j] = f2b_rn(a0[j]); av[4 + j] = f2b_rn(a1[j]); }
            *(u16x8*)&As[buf][arow * 32 + aq * 8] = av;
            u16x8 bv0, bv1;
#pragma unroll
            for (int j = 0; j < 4; j++) { bv0[j] = f2b_rn(b0[j]); bv0[4 + j] = f2b_rn(b1[j]); }
#pragma unroll
            for (int j = 0; j < 4; j++) { bv1[j] = f2b_rn(b2[j]); bv1[4 + j] = f2b_rn(b3[j]); }
            *(u16x8*)&Bs[buf][bcol * 32 + bh * 16] = bv0;
            *(u16x8*)&Bs[buf][bcol * 32 + bh * 16 + 8] = bv1;
        }
        if (ks < 7) ISSUE((ks + 1) * 32);
        __syncthreads();

        bf16x8 af[4], bfr[4];
#pragma unroll
        for (int mi = 0; mi < 4; mi++)
            af[mi] = *(const bf16x8*)&As[buf][(wm * 64 + mi * 16 + r) * 32 + g * 8];
#pragma unroll
        for (int ni = 0; ni < 4; ni++)
            bfr[ni] = *(const bf16x8*)&Bs[buf][(wn * 64 + ni * 16 + r) * 32 + g * 8];
#pragma unroll
        for (int mi = 0; mi < 4; mi++)
#pragma unroll
            for (int ni = 0; ni < 4; ni++)
                acc[mi][ni] = __builtin_amdgcn_mfma_f32_16x16x32_bf16(af[mi], bfr[ni], acc[mi][ni], 0, 0, 0);
    }
#undef ISSUE

#pragma unroll
    for (int ni = 0; ni < 4; ni++) {
        int col = wn * 64 + ni * 16 + r;
        float bv = bias[col];
#pragma unroll
        for (int mi = 0; mi < 4; mi++) {
#pragma unroll
            for (int rr = 0; rr < 4; rr++) {
                int row = m0 + wm * 64 + mi * 16 + g * 4 + rr;
                out[(size_t)row * 256 + col] = f2b_rn(acc[mi][ni][rr] + bv);
            }
        }
    }
}

// ---------------------------------------------------------------------------
// Generic GEMM: out[M,N] = (A (+A2)) @ W^T + bias, bf16 MFMA, fp32 accumulate.
// ---------------------------------------------------------------------------
template<int RELU, int ADD2, int OUTBF16>
__global__ __launch_bounds__(256) void gemm_kernel(
    const float* __restrict__ A, const float* __restrict__ A2,
    const float* __restrict__ W, const float* __restrict__ bias,
    void* __restrict__ outp, int M, int N, int K)
{
    int wave = threadIdx.x >> 6;
    int lane = threadIdx.x & 63;
    int wm = wave >> 1, wn = wave & 1;
    int m0 = blockIdx.x * 64 + wm * 32;
    int n0 = blockIdx.y * 64 + wn * 32;
    int r = lane & 15;   // A row / B col within 16
    int g = lane >> 4;   // k group (x8)

    f32x4 acc[2][2] = {};

    for (int kk = 0; kk < K; kk += 32) {
        int kbase = kk + g * 8;
        bf16x8 af[2], wf[2];
#pragma unroll
        for (int mi = 0; mi < 2; mi++) {
            int row = m0 + mi * 16 + r; if (row >= M) row = M - 1;
            const float* ap = A + (size_t)row * K + kbase;
            if (ADD2) {
                const float* ap2 = A2 + (size_t)row * K + kbase;
#pragma unroll
                for (int j = 0; j < 8; j++) af[mi][j] = (short)f2bf(ap[j] + ap2[j]);
            } else {
#pragma unroll
                for (int j = 0; j < 8; j++) af[mi][j] = (short)f2bf(ap[j]);
            }
        }
#pragma unroll
        for (int ni = 0; ni < 2; ni++) {
            int col = n0 + ni * 16 + r; if (col >= N) col = N - 1;
            const float* wp = W + (size_t)col * K + kbase;
#pragma unroll
            for (int j = 0; j < 8; j++) wf[ni][j] = (short)f2bf(wp[j]);
        }
#pragma unroll
        for (int mi = 0; mi < 2; mi++)
#pragma unroll
            for (int ni = 0; ni < 2; ni++)
                acc[mi][ni] = __builtin_amdgcn_mfma_f32_16x16x32_bf16(af[mi], wf[ni], acc[mi][ni], 0, 0, 0);
    }

    float* outf = (float*)outp;
    unsigned short* outb = (unsigned short*)outp;
#pragma unroll
    for (int mi = 0; mi < 2; mi++)
#pragma unroll
        for (int ni = 0; ni < 2; ni++) {
            int col = n0 + ni * 16 + r;
            if (col < N) {
                float bv = bias ? bias[col] : 0.f;
#pragma unroll
                for (int rr = 0; rr < 4; rr++) {
                    int row = m0 + mi * 16 + g * 4 + rr;
                    if (row < M) {
                        float v = acc[mi][ni][rr] + bv;
                        if (RELU) v = fmaxf(v, 0.f);
                        size_t idx = (size_t)row * N + col;
                        if (OUTBF16) outb[idx] = f2bf(v); else outf[idx] = v;
                    }
                }
            }
        }
}

// ---------------------------------------------------------------------------
// Self-attention over T=6 frames, per (query, head). One block per q (300).
// ---------------------------------------------------------------------------
__global__ __launch_bounds__(256) void selfattn_kernel(
    const float* __restrict__ qh, const float* __restrict__ kh,
    const float* __restrict__ vh, float* __restrict__ sa)
{
    int q = blockIdx.x;
    int tid = threadIdx.x;
    __shared__ float qs[T_][D_], ks[T_][D_], vs[T_][D_];
#pragma unroll
    for (int i = 0; i < T_; i++) {
        size_t base = (size_t)(i * Q_ + q) * D_ + tid;
        qs[i][tid] = qh[base]; ks[i][tid] = kh[base]; vs[i][tid] = vh[base];
    }
    __syncthreads();

    const float scale = 0.17677669529663687f; // 1/sqrt(32)
    float lg[T_][T_];
#pragma unroll
    for (int i = 0; i < T_; i++)
#pragma unroll
        for (int j = 0; j < T_; j++) {
            float p = qs[i][tid] * ks[j][tid];
#pragma unroll
            for (int m = 16; m >= 1; m >>= 1) p += __shfl_xor(p, m, 32);
            lg[i][j] = p * scale;
        }
    float o[T_];
#pragma unroll
    for (int i = 0; i < T_; i++) {
        float mx = lg[i][0];
#pragma unroll
        for (int j = 1; j < T_; j++) mx = fmaxf(mx, lg[i][j]);
        float w[T_]; float sum = 0.f;
#pragma unroll
        for (int j = 0; j < T_; j++) { w[j] = __expf(lg[i][j] - mx); sum += w[j]; }
        float inv = 1.f / sum;
        float a = 0.f;
#pragma unroll
        for (int j = 0; j < T_; j++) a += w[j] * inv * vs[j][tid];
        o[i] = a;
    }
#pragma unroll
    for (int i = 0; i < T_; i++) sa[(size_t)(i * Q_ + q) * D_ + tid] = o[i];
}

// ---------------------------------------------------------------------------
// LayerNorm: out = LN(x1 + x2) * g + b ; optionally out2 = out + add2.
// ---------------------------------------------------------------------------
__global__ __launch_bounds__(256) void ln_kernel(
    const float* __restrict__ x1, const float* __restrict__ x2,
    const float* __restrict__ gam, const float* __restrict__ bet,
    float* __restrict__ out, const float* __restrict__ add2, float* __restrict__ out2)
{
    int row = blockIdx.x;
    int tid = threadIdx.x;
    size_t idx = (size_t)row * D_ + tid;
    float v = x1[idx] + x2[idx];
    __shared__ float red[4];
    float s = v;
#pragma unroll
    for (int m = 32; m >= 1; m >>= 1) s += __shfl_xor(s, m, 64);
    if ((tid & 63) == 0) red[tid >> 6] = s;
    __syncthreads();
    float mu = (red[0] + red[1] + red[2] + red[3]) * (1.f / 256.f);
    __syncthreads();
    float dv = v - mu;
    float s2 = dv * dv;
#pragma unroll
    for (int m = 32; m >= 1; m >>= 1) s2 += __shfl_xor(s2, m, 64);
    if ((tid & 63) == 0) red[tid >> 6] = s2;
    __syncthreads();
    float var = (red[0] + red[1] + red[2] + red[3]) * (1.f / 256.f);
    float y = dv * rsqrtf(var + 1e-5f) * gam[tid] + bet[tid];
    out[idx] = y;
    if (out2) out2[idx] = y + add2[idx];
}

// ---------------------------------------------------------------------------
// Deformable sampling + attention-weighted accumulation.
// ---------------------------------------------------------------------------
__global__ __launch_bounds__(256) void sample_kernel(
    const unsigned short* __restrict__ value, const float* __restrict__ attl,
    const float* __restrict__ off, const float* __restrict__ refp,
    const float* __restrict__ vr, float* __restrict__ out)
{
    int q = blockIdx.x;
    int tid = threadIdx.x;
    int d = tid & 31, h = tid >> 5;
    int t = q / Q_, qq = q - t * Q_;

    __shared__ float aw[NH_][28], ofx[NH_][28], ofy[NH_][28];

    float lgv = (d < 28) ? attl[(size_t)q * 224 + h * 28 + d] : -1e30f;
    float mx = lgv;
#pragma unroll
    for (int m = 16; m >= 1; m >>= 1) mx = fmaxf(mx, __shfl_xor(mx, m, 32));
    float e = (d < 28) ? __expf(lgv - mx) : 0.f;
    float s = e;
#pragma unroll
    for (int m = 16; m >= 1; m >>= 1) s += __shfl_xor(s, m, 32);
    if (d < 28) {
        aw[h][d] = e / s;
        ofx[h][d] = off[(size_t)q * 448 + h * 56 + d * 2 + 0];
        ofy[h][d] = off[(size_t)q * 448 + h * 56 + d * 2 + 1];
    }
    __syncthreads();

    const int WLs[4] = {128, 64, 32, 16};
    const int LST[4] = {0, 98304, 122880, 129024};

    float acc = 0.f;
#pragma unroll
    for (int l = 0; l < L_; l++) {
        const int Wl = WLs[l], Hl = WLs[l];
        const int lst = LST[l];
        float vrx = vr[l * 2 + 0], vry = vr[l * 2 + 1];
#pragma unroll
        for (int p = 0; p < P_; p++) {
            int f = (p < 2) ? t : (((p - 2) < t) ? (p - 2) : (p - 1));
            float rx = refp[(size_t)(f * Q_ + qq) * 2 + 0];
            float ry = refp[(size_t)(f * Q_ + qq) * 2 + 1];
            int ip = l * 7 + p;
            float x = rx * vrx * (float)Wl + ofx[h][ip] - 0.5f;
            float y = ry * vry * (float)Hl + ofy[h][ip] - 0.5f;
            float x0f = floorf(x), y0f = floorf(y);
            float fx = x - x0f, fy = y - y0f;
            int x0 = (int)x0f, y0 = (int)y0f;
            int fbase = lst + f * Hl * Wl;
            float a = aw[h][ip];
#pragma unroll
            for (int dy = 0; dy < 2; dy++) {
                int yi = y0 + dy;
                float wy = dy ? fy : 1.f - fy;
                int yc = min(max(yi, 0), Hl - 1);
                bool oky = (yi >= 0) && (yi < Hl);
#pragma unroll
                for (int dx = 0; dx < 2; dx++) {
                    int xi = x0 + dx;
                    float wx = dx ? fx : 1.f - fx;
                    int xc = min(max(xi, 0), Wl - 1);
                    bool ok = oky && (xi >= 0) && (xi < Wl);
                    float v = bf2f(value[((size_t)(fbase + yc * Wl + xc)) * D_ + h * DH_ + d]);
                    acc += a * (ok ? (wy * wx) : 0.f) * v;
                }
            }
        }
    }
    out[(size_t)q * D_ + tid] = acc;
}

// ---------------------------------------------------------------------------
extern "C" void kernel_launch(void* const* d_in, const int* in_sizes, int n_in,
                              void* d_out, int out_size, void* d_ws, size_t ws_size,
                              hipStream_t stream) {
    const float* src  = (const float*)d_in[0];
    const float* tgtm = (const float*)d_in[1];
    const float* qpos = (const float*)d_in[2];
    const float* refp = (const float*)d_in[3];
    const float* vr   = (const float*)d_in[4];   // use frame-0 slice: first 8 floats
    const float* Wq = (const float*)d_in[7];  const float* bq = (const float*)d_in[8];
    const float* Wk = (const float*)d_in[9];  const float* bk = (const float*)d_in[10];
    const float* Wv = (const float*)d_in[11]; const float* bv = (const float*)d_in[12];
    const float* Wo = (const float*)d_in[13]; const float* bo = (const float*)d_in[14];
    const float* n2g = (const float*)d_in[15]; const float* n2b = (const float*)d_in[16];
    const float* Wval = (const float*)d_in[17]; const float* bval = (const float*)d_in[18];
    const float* Woff = (const float*)d_in[19]; const float* boff = (const float*)d_in[20];
    const float* Watt = (const float*)d_in[21]; const float* batt = (const float*)d_in[22];
    const float* Wout = (const float*)d_in[23]; const float* bout = (const float*)d_in[24];
    const float* n1g = (const float*)d_in[25]; const float* n1b = (const float*)d_in[26];
    const float* W1 = (const float*)d_in[27]; const float* b1 = (const float*)d_in[28];
    const float* W2 = (const float*)d_in[29]; const float* b2 = (const float*)d_in[30];
    const float* n3g = (const float*)d_in[31]; const float* n3b = (const float*)d_in[32];

    char* ws = (char*)d_ws;
    size_t o = 0;
    auto alloc = [&](size_t bytes) -> void* {
        void* p = ws + o; o += (bytes + 255) & ~(size_t)255; return p;
    };
    unsigned short* value = (unsigned short*)alloc((size_t)NV * D_ * 2);
    float* qh     = (float*)alloc((size_t)TQ * D_ * 4);
    float* kh     = (float*)alloc((size_t)TQ * D_ * 4);
    float* vh     = (float*)alloc((size_t)TQ * D_ * 4);
    float* sa_raw = (float*)alloc((size_t)TQ * D_ * 4);
    float* saproj = (float*)alloc((size_t)TQ * D_ * 4);
    float* tgt1   = (float*)alloc((size_t)TQ * D_ * 4);
    float* query  = (float*)alloc((size_t)TQ * D_ * 4);
    float* offb   = (float*)alloc((size_t)TQ * 448 * 4);
    float* attl   = (float*)alloc((size_t)TQ * 224 * 4);
    float* samp   = (float*)alloc((size_t)TQ * D_ * 4);
    float* cross  = (float*)alloc((size_t)TQ * D_ * 4);
    float* tgt2   = (float*)alloc((size_t)TQ * D_ * 4);
    float* hbuf   = (float*)alloc((size_t)TQ * DFF_ * 4);
    float* ffo    = (float*)alloc((size_t)TQ * D_ * 4);

    dim3 B(256);
    const int MT = (TQ + 63) / 64;  // 29

    // Big value projection (independent of everything else): NV x 256, bf16 out
    vgemm_kernel<<<dim3(NV / 128), dim3(512), 0, stream>>>(src, Wval, bval, value);

    // Self-attention branch
    gemm_kernel<0,1,0><<<dim3(MT, 4), B, 0, stream>>>(tgtm, qpos, Wq, bq, qh, TQ, D_, D_);
    gemm_kernel<0,1,0><<<dim3(MT, 4), B, 0, stream>>>(tgtm, qpos, Wk, bk, kh, TQ, D_, D_);
    gemm_kernel<0,0,0><<<dim3(MT, 4), B, 0, stream>>>(tgtm, nullptr, Wv, bv, vh, TQ, D_, D_);
    selfattn_kernel<<<dim3(Q_), B, 0, stream>>>(qh, kh, vh, sa_raw);
    gemm_kernel<0,0,0><<<dim3(MT, 4), B, 0, stream>>>(sa_raw, nullptr, Wo, bo, saproj, TQ, D_, D_);
    ln_kernel<<<dim3(TQ), B, 0, stream>>>(tgtm, saproj, n2g, n2b, tgt1, qpos, query);

    // Deformable cross-attention
    gemm_kernel<0,0,0><<<dim3(MT, 7), B, 0, stream>>>(query, nullptr, Woff, boff, offb, TQ, 448, D_);
    gemm_kernel<0,0,0><<<dim3(MT, 4), B, 0, stream>>>(query, nullptr, Watt, batt, attl, TQ, 224, D_);
    sample_kernel<<<dim3(TQ), B, 0, stream>>>(value, attl, offb, refp, vr, samp);
    gemm_kernel<0,0,0><<<dim3(MT, 4), B, 0, stream>>>(samp, nullptr, Wout, bout, cross, TQ, D_, D_);
    ln_kernel<<<dim3(TQ), B, 0, stream>>>(tgt1, cross, n1g, n1b, tgt2, nullptr, nullptr);

    // FFN
    gemm_kernel<1,0,0><<<dim3(MT, 16), B, 0, stream>>>(tgt2, nullptr, W1, b1, hbuf, TQ, DFF_, D_);
    gemm_kernel<0,0,0><<<dim3(MT, 4), B, 0, stream>>>(hbuf, nullptr, W2, b2, ffo, TQ, D_, DFF_);
    ln_kernel<<<dim3(TQ), B, 0, stream>>>(tgt2, ffo, n3g, n3b, (float*)d_out, nullptr, nullptr);
}